// Round 1
// baseline (180.171 us; speedup 1.0000x reference)
//
#include <hip/hip_runtime.h>
#include <math.h>

#define PNUM 512
#define IMW 256
#define IMH 256

// ws layout (floats): [0]=mx[512], [512]=my, [1024]=cA, [1536]=cB, [2048]=cC,
// [2560]=op, [3072]=cr, [3584]=cg, [4096]=cb, then int nvis at float index 4608.

__global__ __launch_bounds__(512) void gr_preprocess(
    const float* __restrict__ points, const float* __restrict__ scales,
    const float* __restrict__ rots, const float* __restrict__ opac_in,
    const float* __restrict__ shs, const float* __restrict__ vm,
    float* __restrict__ out, float* __restrict__ ws)
{
    __shared__ float s_key[PNUM];
    __shared__ int s_cnt;
    const int i = threadIdx.x;
    if (i == 0) s_cnt = 0;
    __syncthreads();

    // ---- load inputs ----
    const float px = points[3*i], py = points[3*i+1], pz = points[3*i+2];
    const float sx = expf(scales[3*i]), sy = expf(scales[3*i+1]), sz = expf(scales[3*i+2]);
    const float op0 = 1.0f / (1.0f + expf(-opac_in[i]));
    float q0 = rots[4*i], q1 = rots[4*i+1], q2 = rots[4*i+2], q3 = rots[4*i+3];
    const float inv = 1.0f / sqrtf(q0*q0 + q1*q1 + q2*q2 + q3*q3);
    const float r = q0*inv, x = q1*inv, y = q2*inv, z = q3*inv;

    // ---- rotation matrix ----
    const float R00 = 1.f - 2.f*(y*y + z*z);
    const float R01 = 2.f*(x*y - r*z);
    const float R02 = 2.f*(x*z + r*y);
    const float R10 = 2.f*(x*y + r*z);
    const float R11 = 1.f - 2.f*(x*x + z*z);
    const float R12 = 2.f*(y*z - r*x);
    const float R20 = 2.f*(x*z - r*y);
    const float R21 = 2.f*(y*z + r*x);
    const float R22 = 1.f - 2.f*(x*x + y*y);

    // M = R * diag(s)  (column scaling)
    const float M00=R00*sx, M01=R01*sy, M02=R02*sz;
    const float M10=R10*sx, M11=R11*sy, M12=R12*sz;
    const float M20=R20*sx, M21=R21*sy, M22=R22*sz;

    // Sigma = M M^T (symmetric)
    const float S00 = M00*M00 + M01*M01 + M02*M02;
    const float S01 = M00*M10 + M01*M11 + M02*M12;
    const float S02 = M00*M20 + M01*M21 + M02*M22;
    const float S11 = M10*M10 + M11*M11 + M12*M12;
    const float S12 = M10*M20 + M11*M21 + M12*M22;
    const float S22 = M20*M20 + M21*M21 + M22*M22;

    // view transform (row-major 4x4)
    const float W00=vm[0], W01=vm[1], W02=vm[2],  T0=vm[3];
    const float W10=vm[4], W11=vm[5], W12=vm[6],  T1=vm[7];
    const float W20=vm[8], W21=vm[9], W22=vm[10], T2=vm[11];
    const float tx = W00*px + W01*py + W02*pz + T0;
    const float ty = W10*px + W11*py + W12*pz + T1;
    const float tz = W20*px + W21*py + W22*pz + T2;

    bool vis = tz > 0.2f;
    const float tzs = vis ? tz : 1.0f;
    const float lim = 1.3f * 0.5f;
    const float txtz = fminf(fmaxf(tx / tzs, -lim), lim) * tzs;
    const float tytz = fminf(fmaxf(ty / tzs, -lim), lim) * tzs;

    const float FX = 256.0f, FY = 256.0f;
    const float J00 = FX / tzs;
    const float J02 = -FX * txtz / (tzs * tzs);
    const float J11 = FY / tzs;
    const float J12 = -FY * tytz / (tzs * tzs);

    // Tm = J @ Wrot (2x3)
    const float Tm00 = J00*W00 + J02*W20;
    const float Tm01 = J00*W01 + J02*W21;
    const float Tm02 = J00*W02 + J02*W22;
    const float Tm10 = J11*W10 + J12*W20;
    const float Tm11 = J11*W11 + J12*W21;
    const float Tm12 = J11*W12 + J12*W22;

    // U = Tm @ Sigma
    const float U00 = Tm00*S00 + Tm01*S01 + Tm02*S02;
    const float U01 = Tm00*S01 + Tm01*S11 + Tm02*S12;
    const float U02 = Tm00*S02 + Tm01*S12 + Tm02*S22;
    const float U10 = Tm10*S00 + Tm11*S01 + Tm12*S02;
    const float U11 = Tm10*S01 + Tm11*S11 + Tm12*S12;
    const float U12 = Tm10*S02 + Tm11*S12 + Tm12*S22;

    // cov = U @ Tm^T (2x2)
    const float cov00 = U00*Tm00 + U01*Tm01 + U02*Tm02;
    const float cov01 = U00*Tm10 + U01*Tm11 + U02*Tm12;
    const float cov11 = U10*Tm10 + U11*Tm11 + U12*Tm12;

    const float det_orig = cov00*cov11 - cov01*cov01;
    const float a = cov00 + 0.3f, c = cov11 + 0.3f, b = cov01;
    const float det = a*c - b*b;
    vis = vis && (det > 0.f);
    const float dets = (det > 0.f) ? det : 1.0f;
    const float comp = sqrtf(fmaxf(det_orig / dets, 0.f));
    const float op = vis ? op0 * comp : 0.f;
    const float cA = c / dets, cB = -b / dets, cC = a / dets;

    const float mid = 0.5f * (a + c);
    const float lam = mid + sqrtf(fmaxf(mid*mid - det, 0.1f));
    const float radii = vis ? ceilf(3.f * sqrtf(lam)) : 0.f;

    const float mx = FX * tx / tzs + (IMW - 1) * 0.5f;
    const float my = FY * ty / tzs + (IMH - 1) * 0.5f;

    const float SH_C0 = 0.28209479177387814f;
    const float cr = fmaxf(shs[3*i  ] * SH_C0 + 0.5f, 0.f);
    const float cg = fmaxf(shs[3*i+1] * SH_C0 + 0.5f, 0.f);
    const float cb = fmaxf(shs[3*i+2] * SH_C0 + 0.5f, 0.f);

    // ---- stable depth sort by rank (O(P^2), one block) ----
    const float key = vis ? tz : __builtin_inff();
    s_key[i] = key;
    if (vis) atomicAdd(&s_cnt, 1);
    __syncthreads();

    int rank = 0;
    #pragma unroll 8
    for (int j = 0; j < PNUM; ++j) {
        const float kj = s_key[j];
        rank += (kj < key || (kj == key && j < i)) ? 1 : 0;
    }

    ws[0*PNUM + rank] = mx;
    ws[1*PNUM + rank] = my;
    ws[2*PNUM + rank] = cA;
    ws[3*PNUM + rank] = cB;
    ws[4*PNUM + rank] = cC;
    ws[5*PNUM + rank] = op;
    ws[6*PNUM + rank] = cr;
    ws[7*PNUM + rank] = cg;
    ws[8*PNUM + rank] = cb;
    if (i == 0) ((int*)ws)[9*PNUM] = s_cnt;

    // ---- aux outputs: viewspace_points (zeros) + radii (as f32) ----
    out[196608 + 3*i + 0] = 0.f;
    out[196608 + 3*i + 1] = 0.f;
    out[196608 + 3*i + 2] = 0.f;
    out[198144 + i] = radii;
}

__global__ __launch_bounds__(256) void gr_rasterize(
    const float* __restrict__ ws, float* __restrict__ out)
{
    __shared__ float sm[9 * PNUM];
    __shared__ int s_n;
    const int tid = threadIdx.x;

    for (int idx = tid; idx < 9 * PNUM; idx += 256) sm[idx] = ws[idx];
    if (tid == 0) s_n = ((const int*)ws)[9 * PNUM];
    __syncthreads();

    const float* s_mx = sm + 0*PNUM;
    const float* s_my = sm + 1*PNUM;
    const float* s_cA = sm + 2*PNUM;
    const float* s_cB = sm + 3*PNUM;
    const float* s_cC = sm + 4*PNUM;
    const float* s_op = sm + 5*PNUM;
    const float* s_cr = sm + 6*PNUM;
    const float* s_cg = sm + 7*PNUM;
    const float* s_cb = sm + 8*PNUM;
    const int n = s_n;

    const float fx = (float)tid;
    const float fy = (float)blockIdx.x;

    float accr = 0.f, accg = 0.f, accb = 0.f;
    float T = 1.f;

    for (int k = 0; k < n; ++k) {
        const float dx = fx - s_mx[k];
        const float dy = fy - s_my[k];
        const float power = -0.5f * (s_cA[k]*dx*dx + s_cC[k]*dy*dy) - s_cB[k]*dx*dy;
        if (power > 0.f) continue;
        float alpha = fminf(0.99f, s_op[k] * __expf(power));
        if (alpha < (1.0f / 255.0f)) continue;
        const float w = alpha * T;
        accr = fmaf(w, s_cr[k], accr);
        accg = fmaf(w, s_cg[k], accg);
        accb = fmaf(w, s_cb[k], accb);
        T *= (1.f - alpha);
        if (T < 1e-4f) break;
    }

    const int pix = blockIdx.x * IMW + tid;
    out[pix] = accr;
    out[65536 + pix] = accg;
    out[131072 + pix] = accb;
}

extern "C" void kernel_launch(void* const* d_in, const int* in_sizes, int n_in,
                              void* d_out, int out_size, void* d_ws, size_t ws_size,
                              hipStream_t stream) {
    const float* points = (const float*)d_in[0];
    const float* scales = (const float*)d_in[1];
    const float* rots   = (const float*)d_in[2];
    const float* opac   = (const float*)d_in[3];
    const float* shs    = (const float*)d_in[4];
    const float* vm     = (const float*)d_in[5];
    float* out = (float*)d_out;
    float* ws  = (float*)d_ws;

    gr_preprocess<<<1, PNUM, 0, stream>>>(points, scales, rots, opac, shs, vm, out, ws);
    gr_rasterize<<<IMH, IMW, 0, stream>>>(ws, out);
}

// Round 2
// 101.707 us; speedup vs baseline: 1.7715x; 1.7715x over previous
//
#include <hip/hip_runtime.h>
#include <math.h>

#define PNUM 512
#define IMW 256
#define IMH 256
#define NCH 8      // gaussian chunks (waves per rasterize block)
#define SEGW 64    // pixels per rasterize block

// ws layout (floats): [0]=mx[512], [512]=my, [1024]=A2(-0.5A), [1536]=B2(-B),
// [2048]=C2(-0.5C), [2560]=op, [3072]=cr, [3584]=cg, [4096]=cb,
// int nvis at float index 4608.

__global__ __launch_bounds__(512) void gr_preprocess(
    const float* __restrict__ points, const float* __restrict__ scales,
    const float* __restrict__ rots, const float* __restrict__ opac_in,
    const float* __restrict__ shs, const float* __restrict__ vm,
    float* __restrict__ out, float* __restrict__ ws)
{
    __shared__ float s_key[PNUM];
    __shared__ int s_cnt;
    const int i = threadIdx.x;
    if (i == 0) s_cnt = 0;
    __syncthreads();

    // ---- load inputs ----
    const float px = points[3*i], py = points[3*i+1], pz = points[3*i+2];
    const float sx = expf(scales[3*i]), sy = expf(scales[3*i+1]), sz = expf(scales[3*i+2]);
    const float op0 = 1.0f / (1.0f + expf(-opac_in[i]));
    float q0 = rots[4*i], q1 = rots[4*i+1], q2 = rots[4*i+2], q3 = rots[4*i+3];
    const float inv = 1.0f / sqrtf(q0*q0 + q1*q1 + q2*q2 + q3*q3);
    const float r = q0*inv, x = q1*inv, y = q2*inv, z = q3*inv;

    // ---- rotation matrix ----
    const float R00 = 1.f - 2.f*(y*y + z*z);
    const float R01 = 2.f*(x*y - r*z);
    const float R02 = 2.f*(x*z + r*y);
    const float R10 = 2.f*(x*y + r*z);
    const float R11 = 1.f - 2.f*(x*x + z*z);
    const float R12 = 2.f*(y*z - r*x);
    const float R20 = 2.f*(x*z - r*y);
    const float R21 = 2.f*(y*z + r*x);
    const float R22 = 1.f - 2.f*(x*x + y*y);

    // M = R * diag(s)
    const float M00=R00*sx, M01=R01*sy, M02=R02*sz;
    const float M10=R10*sx, M11=R11*sy, M12=R12*sz;
    const float M20=R20*sx, M21=R21*sy, M22=R22*sz;

    // Sigma = M M^T
    const float S00 = M00*M00 + M01*M01 + M02*M02;
    const float S01 = M00*M10 + M01*M11 + M02*M12;
    const float S02 = M00*M20 + M01*M21 + M02*M22;
    const float S11 = M10*M10 + M11*M11 + M12*M12;
    const float S12 = M10*M20 + M11*M21 + M12*M22;
    const float S22 = M20*M20 + M21*M21 + M22*M22;

    const float W00=vm[0], W01=vm[1], W02=vm[2],  T0=vm[3];
    const float W10=vm[4], W11=vm[5], W12=vm[6],  T1=vm[7];
    const float W20=vm[8], W21=vm[9], W22=vm[10], T2=vm[11];
    const float tx = W00*px + W01*py + W02*pz + T0;
    const float ty = W10*px + W11*py + W12*pz + T1;
    const float tz = W20*px + W21*py + W22*pz + T2;

    bool vis = tz > 0.2f;
    const float tzs = vis ? tz : 1.0f;
    const float lim = 1.3f * 0.5f;
    const float txtz = fminf(fmaxf(tx / tzs, -lim), lim) * tzs;
    const float tytz = fminf(fmaxf(ty / tzs, -lim), lim) * tzs;

    const float FX = 256.0f, FY = 256.0f;
    const float J00 = FX / tzs;
    const float J02 = -FX * txtz / (tzs * tzs);
    const float J11 = FY / tzs;
    const float J12 = -FY * tytz / (tzs * tzs);

    const float Tm00 = J00*W00 + J02*W20;
    const float Tm01 = J00*W01 + J02*W21;
    const float Tm02 = J00*W02 + J02*W22;
    const float Tm10 = J11*W10 + J12*W20;
    const float Tm11 = J11*W11 + J12*W21;
    const float Tm12 = J11*W12 + J12*W22;

    const float U00 = Tm00*S00 + Tm01*S01 + Tm02*S02;
    const float U01 = Tm00*S01 + Tm01*S11 + Tm02*S12;
    const float U02 = Tm00*S02 + Tm01*S12 + Tm02*S22;
    const float U10 = Tm10*S00 + Tm11*S01 + Tm12*S02;
    const float U11 = Tm10*S01 + Tm11*S11 + Tm12*S12;
    const float U12 = Tm10*S02 + Tm11*S12 + Tm12*S22;

    const float cov00 = U00*Tm00 + U01*Tm01 + U02*Tm02;
    const float cov01 = U00*Tm10 + U01*Tm11 + U02*Tm12;
    const float cov11 = U10*Tm10 + U11*Tm11 + U12*Tm12;

    const float det_orig = cov00*cov11 - cov01*cov01;
    const float a = cov00 + 0.3f, c = cov11 + 0.3f, b = cov01;
    const float det = a*c - b*b;
    vis = vis && (det > 0.f);
    const float dets = (det > 0.f) ? det : 1.0f;
    const float comp = sqrtf(fmaxf(det_orig / dets, 0.f));
    const float op = vis ? op0 * comp : 0.f;
    const float cA = c / dets, cB = -b / dets, cC = a / dets;

    const float mid = 0.5f * (a + c);
    const float lam = mid + sqrtf(fmaxf(mid*mid - det, 0.1f));
    const float radii = vis ? ceilf(3.f * sqrtf(lam)) : 0.f;

    const float mx = FX * tx / tzs + (IMW - 1) * 0.5f;
    const float my = FY * ty / tzs + (IMH - 1) * 0.5f;

    const float SH_C0 = 0.28209479177387814f;
    const float cr = fmaxf(shs[3*i  ] * SH_C0 + 0.5f, 0.f);
    const float cg = fmaxf(shs[3*i+1] * SH_C0 + 0.5f, 0.f);
    const float cb = fmaxf(shs[3*i+2] * SH_C0 + 0.5f, 0.f);

    // ---- stable depth sort by rank (O(P^2), one block) ----
    const float key = vis ? tz : __builtin_inff();
    s_key[i] = key;
    if (vis) atomicAdd(&s_cnt, 1);
    __syncthreads();

    int rank = 0;
    #pragma unroll 8
    for (int j = 0; j < PNUM; ++j) {
        const float kj = s_key[j];
        rank += (kj < key || (kj == key && j < i)) ? 1 : 0;
    }

    ws[0*PNUM + rank] = mx;
    ws[1*PNUM + rank] = my;
    ws[2*PNUM + rank] = -0.5f * cA;   // A2
    ws[3*PNUM + rank] = -cB;          // B2
    ws[4*PNUM + rank] = -0.5f * cC;   // C2
    ws[5*PNUM + rank] = op;
    ws[6*PNUM + rank] = cr;
    ws[7*PNUM + rank] = cg;
    ws[8*PNUM + rank] = cb;
    if (i == 0) ((int*)ws)[9*PNUM] = s_cnt;

    out[196608 + 3*i + 0] = 0.f;
    out[196608 + 3*i + 1] = 0.f;
    out[196608 + 3*i + 2] = 0.f;
    out[198144 + i] = radii;
}

// One block = 64 pixels (a 64-wide row segment) x 8 waves.
// Wave c composites gaussian chunk [c*64, (c+1)*64) for all 64 pixels;
// partial (rgb, T) per chunk merged in LDS in chunk order (associative).
__global__ __launch_bounds__(512) void gr_rasterize(
    const float* __restrict__ ws, float* __restrict__ out)
{
    __shared__ float sm[9 * PNUM];
    __shared__ float pr[NCH * SEGW], pg[NCH * SEGW], pb[NCH * SEGW], pt[NCH * SEGW];
    __shared__ int s_n;
    const int tid = threadIdx.x;

    for (int idx = tid; idx < 9 * PNUM; idx += 512) sm[idx] = ws[idx];
    if (tid == 0) s_n = ((const int*)ws)[9 * PNUM];
    __syncthreads();

    const float* s_mx = sm + 0*PNUM;
    const float* s_my = sm + 1*PNUM;
    const float* s_A  = sm + 2*PNUM;
    const float* s_B  = sm + 3*PNUM;
    const float* s_C  = sm + 4*PNUM;
    const float* s_op = sm + 5*PNUM;
    const float* s_cr = sm + 6*PNUM;
    const float* s_cg = sm + 7*PNUM;
    const float* s_cb = sm + 8*PNUM;
    const int n = s_n;

    const int wave = tid >> 6;        // chunk id 0..7
    const int lane = tid & 63;        // pixel within segment
    const int seg  = blockIdx.x;      // 0..1023
    const int row  = seg >> 2;
    const int x0   = (seg & 3) << 6;

    const float fx = (float)(x0 + lane);
    const float fy = (float)row;

    float T = 1.f, r = 0.f, g = 0.f, b = 0.f;
    const int k0 = wave * SEGW;
    const int k1 = (k0 + SEGW < n) ? (k0 + SEGW) : n;

    for (int k = k0; k < k1; ++k) {
        const float dx = fx - s_mx[k];
        const float dy = fy - s_my[k];
        // power = A2*dx^2 + B2*dx*dy + C2*dy^2  (A2=-0.5A, B2=-B, C2=-0.5C)
        const float power = fmaf(s_A[k], dx*dx, fmaf(s_B[k], dx*dy, s_C[k]*dy*dy));
        if (power > 0.f) continue;
        const float alpha = fminf(0.99f, s_op[k] * __expf(power));
        if (alpha < (1.0f / 255.0f)) continue;
        const float w = alpha * T;
        r = fmaf(w, s_cr[k], r);
        g = fmaf(w, s_cg[k], g);
        b = fmaf(w, s_cb[k], b);
        T *= (1.f - alpha);
        if (__all(T < 1e-4f)) break;   // remaining chunk contribution < 1e-4
    }

    pr[wave * SEGW + lane] = r;
    pg[wave * SEGW + lane] = g;
    pb[wave * SEGW + lane] = b;
    pt[wave * SEGW + lane] = T;
    __syncthreads();

    // ordered merge of the 8 chunk partials, one thread per pixel
    if (tid < SEGW) {
        float Tc = 1.f, ar = 0.f, ag = 0.f, ab = 0.f;
        #pragma unroll
        for (int c = 0; c < NCH; ++c) {
            ar = fmaf(Tc, pr[c * SEGW + tid], ar);
            ag = fmaf(Tc, pg[c * SEGW + tid], ag);
            ab = fmaf(Tc, pb[c * SEGW + tid], ab);
            Tc *= pt[c * SEGW + tid];
        }
        const int pix = row * IMW + x0 + tid;
        out[pix]          = ar;
        out[65536 + pix]  = ag;
        out[131072 + pix] = ab;
    }
}

extern "C" void kernel_launch(void* const* d_in, const int* in_sizes, int n_in,
                              void* d_out, int out_size, void* d_ws, size_t ws_size,
                              hipStream_t stream) {
    const float* points = (const float*)d_in[0];
    const float* scales = (const float*)d_in[1];
    const float* rots   = (const float*)d_in[2];
    const float* opac   = (const float*)d_in[3];
    const float* shs    = (const float*)d_in[4];
    const float* vm     = (const float*)d_in[5];
    float* out = (float*)d_out;
    float* ws  = (float*)d_ws;

    gr_preprocess<<<1, PNUM, 0, stream>>>(points, scales, rots, opac, shs, vm, out, ws);
    gr_rasterize<<<IMH * (IMW / SEGW), 512, 0, stream>>>(ws, out);
}

// Round 3
// 82.975 us; speedup vs baseline: 2.1714x; 1.2258x over previous
//
#include <hip/hip_runtime.h>
#include <math.h>

#define PNUM 512
#define IMW 256
#define IMH 256
#define NCH 8      // waves per rasterize block
#define SEGW 64    // pixels per rasterize block (one 64-wide row segment)

// ws layout (floats, SoA, depth-sorted): [0]=mx[512], [512]=my, [1024]=A2(-0.5A),
// [1536]=B2(-B), [2048]=C2(-0.5C), [2560]=op, [3072]=cr, [3584]=cg, [4096]=cb,
// [4608]=rc2 (cull radius^2; <0 => never contributes)

__global__ __launch_bounds__(512) void gr_preprocess(
    const float* __restrict__ points, const float* __restrict__ scales,
    const float* __restrict__ rots, const float* __restrict__ opac_in,
    const float* __restrict__ shs, const float* __restrict__ vm,
    float* __restrict__ out, float* __restrict__ ws)
{
    __shared__ float s_key[PNUM];
    const int i = threadIdx.x;

    // ---- load inputs ----
    const float px = points[3*i], py = points[3*i+1], pz = points[3*i+2];
    const float sx = expf(scales[3*i]), sy = expf(scales[3*i+1]), sz = expf(scales[3*i+2]);
    const float op0 = 1.0f / (1.0f + expf(-opac_in[i]));
    float q0 = rots[4*i], q1 = rots[4*i+1], q2 = rots[4*i+2], q3 = rots[4*i+3];
    const float inv = 1.0f / sqrtf(q0*q0 + q1*q1 + q2*q2 + q3*q3);
    const float r = q0*inv, x = q1*inv, y = q2*inv, z = q3*inv;

    const float R00 = 1.f - 2.f*(y*y + z*z);
    const float R01 = 2.f*(x*y - r*z);
    const float R02 = 2.f*(x*z + r*y);
    const float R10 = 2.f*(x*y + r*z);
    const float R11 = 1.f - 2.f*(x*x + z*z);
    const float R12 = 2.f*(y*z - r*x);
    const float R20 = 2.f*(x*z - r*y);
    const float R21 = 2.f*(y*z + r*x);
    const float R22 = 1.f - 2.f*(x*x + y*y);

    const float M00=R00*sx, M01=R01*sy, M02=R02*sz;
    const float M10=R10*sx, M11=R11*sy, M12=R12*sz;
    const float M20=R20*sx, M21=R21*sy, M22=R22*sz;

    const float S00 = M00*M00 + M01*M01 + M02*M02;
    const float S01 = M00*M10 + M01*M11 + M02*M12;
    const float S02 = M00*M20 + M01*M21 + M02*M22;
    const float S11 = M10*M10 + M11*M11 + M12*M12;
    const float S12 = M10*M20 + M11*M21 + M12*M22;
    const float S22 = M20*M20 + M21*M21 + M22*M22;

    const float W00=vm[0], W01=vm[1], W02=vm[2],  T0=vm[3];
    const float W10=vm[4], W11=vm[5], W12=vm[6],  T1=vm[7];
    const float W20=vm[8], W21=vm[9], W22=vm[10], T2=vm[11];
    const float tx = W00*px + W01*py + W02*pz + T0;
    const float ty = W10*px + W11*py + W12*pz + T1;
    const float tz = W20*px + W21*py + W22*pz + T2;

    bool vis = tz > 0.2f;
    const float tzs = vis ? tz : 1.0f;
    const float lim = 1.3f * 0.5f;
    const float txtz = fminf(fmaxf(tx / tzs, -lim), lim) * tzs;
    const float tytz = fminf(fmaxf(ty / tzs, -lim), lim) * tzs;

    const float FX = 256.0f, FY = 256.0f;
    const float J00 = FX / tzs;
    const float J02 = -FX * txtz / (tzs * tzs);
    const float J11 = FY / tzs;
    const float J12 = -FY * tytz / (tzs * tzs);

    const float Tm00 = J00*W00 + J02*W20;
    const float Tm01 = J00*W01 + J02*W21;
    const float Tm02 = J00*W02 + J02*W22;
    const float Tm10 = J11*W10 + J12*W20;
    const float Tm11 = J11*W11 + J12*W21;
    const float Tm12 = J11*W12 + J12*W22;

    const float U00 = Tm00*S00 + Tm01*S01 + Tm02*S02;
    const float U01 = Tm00*S01 + Tm01*S11 + Tm02*S12;
    const float U02 = Tm00*S02 + Tm01*S12 + Tm02*S22;
    const float U10 = Tm10*S00 + Tm11*S01 + Tm12*S02;
    const float U11 = Tm10*S01 + Tm11*S11 + Tm12*S12;
    const float U12 = Tm10*S02 + Tm11*S12 + Tm12*S22;

    const float cov00 = U00*Tm00 + U01*Tm01 + U02*Tm02;
    const float cov01 = U00*Tm10 + U01*Tm11 + U02*Tm12;
    const float cov11 = U10*Tm10 + U11*Tm11 + U12*Tm12;

    const float det_orig = cov00*cov11 - cov01*cov01;
    const float a = cov00 + 0.3f, c = cov11 + 0.3f, b = cov01;
    const float det = a*c - b*b;
    vis = vis && (det > 0.f);
    const float dets = (det > 0.f) ? det : 1.0f;
    const float comp = sqrtf(fmaxf(det_orig / dets, 0.f));
    const float op = vis ? op0 * comp : 0.f;
    const float cA = c / dets, cB = -b / dets, cC = a / dets;

    const float mid = 0.5f * (a + c);
    const float lam = mid + sqrtf(fmaxf(mid*mid - det, 0.1f));
    const float radii = vis ? ceilf(3.f * sqrtf(lam)) : 0.f;

    const float mx = FX * tx / tzs + (IMW - 1) * 0.5f;
    const float my = FY * ty / tzs + (IMH - 1) * 0.5f;

    const float SH_C0 = 0.28209479177387814f;
    const float cr = fmaxf(shs[3*i  ] * SH_C0 + 0.5f, 0.f);
    const float cg = fmaxf(shs[3*i+1] * SH_C0 + 0.5f, 0.f);
    const float cb = fmaxf(shs[3*i+2] * SH_C0 + 0.5f, 0.f);

    // cull radius^2: alpha >= 1/255 requires |d|^2 <= 2*lam*ln(255*op).
    // lam >= lambda_max(cov), so this is a conservative (exact-safe) bound.
    float rc2 = -1.f;
    const float p255 = 255.f * op;
    if (p255 > 1.f) rc2 = 2.f * lam * logf(p255) * 1.001f + 0.01f;

    // ---- stable depth sort by rank (O(P^2), one block) ----
    const float key = vis ? tz : __builtin_inff();
    s_key[i] = key;
    __syncthreads();

    int rank = 0;
    #pragma unroll 8
    for (int j = 0; j < PNUM; ++j) {
        const float kj = s_key[j];
        rank += (kj < key || (kj == key && j < i)) ? 1 : 0;
    }

    ws[0*PNUM + rank] = mx;
    ws[1*PNUM + rank] = my;
    ws[2*PNUM + rank] = -0.5f * cA;   // A2
    ws[3*PNUM + rank] = -cB;          // B2
    ws[4*PNUM + rank] = -0.5f * cC;   // C2
    ws[5*PNUM + rank] = op;
    ws[6*PNUM + rank] = cr;
    ws[7*PNUM + rank] = cg;
    ws[8*PNUM + rank] = cb;
    ws[9*PNUM + rank] = rc2;

    out[196608 + 3*i + 0] = 0.f;
    out[196608 + 3*i + 1] = 0.f;
    out[196608 + 3*i + 2] = 0.f;
    out[198144 + i] = radii;
}

// Block = one 64-px row segment, 512 threads (8 waves).
// Phase 1: thread t tests gaussian t against the segment (exact-safe cull).
// Phase 2: stable ballot-compaction of survivors (depth order preserved).
// Phase 3: 8-wave chunk compositing over the short list + ordered LDS merge.
__global__ __launch_bounds__(512) void gr_rasterize(
    const float* __restrict__ ws, float* __restrict__ out)
{
    __shared__ int slist[PNUM];
    __shared__ int scnt[NCH];
    __shared__ float pr[NCH * SEGW], pg[NCH * SEGW], pb[NCH * SEGW], pt[NCH * SEGW];

    const int tid  = threadIdx.x;
    const int lane = tid & 63;
    const int wv   = tid >> 6;
    const int seg  = blockIdx.x;
    const int row  = seg >> 2;
    const int x0   = (seg & 3) << 6;
    const float fy = (float)row;

    // ---- phase 1: cull test, one gaussian per thread ----
    const float mx  = ws[0*PNUM + tid];
    const float my  = ws[1*PNUM + tid];
    const float rc2 = ws[9*PNUM + tid];
    const float dxl = (float)x0 - mx;          // >0 if center left of segment
    const float dxr = mx - (float)(x0 + SEGW - 1);
    const float dxm = fmaxf(0.f, fmaxf(dxl, dxr));
    const float dym = fabsf(fy - my);
    const bool hit = (dxm*dxm + dym*dym) <= rc2;   // rc2<0 => false

    // ---- phase 2: stable compaction ----
    const unsigned long long m = __ballot(hit);
    if (lane == 0) scnt[wv] = __popcll(m);
    __syncthreads();
    int base = 0;
    #pragma unroll
    for (int w = 0; w < NCH; ++w) if (w < wv) base += scnt[w];
    int L = base;
    #pragma unroll
    for (int w = 0; w < NCH; ++w) if (w >= wv) L += scnt[w];
    if (hit) {
        const int pos = __popcll(m & ((1ull << lane) - 1ull));
        slist[base + pos] = tid;
    }
    __syncthreads();

    // ---- phase 3: chunked front-to-back compositing ----
    const int Lc = (L + NCH - 1) / NCH;
    const int k0 = wv * Lc;
    const int k1 = (k0 + Lc < L) ? (k0 + Lc) : L;

    const float fx = (float)(x0 + lane);
    float T = 1.f, r = 0.f, g = 0.f, b = 0.f;

    for (int k = k0; k < k1; ++k) {
        const int j = slist[k];                 // uniform across wave
        const float gmx = ws[0*PNUM + j];
        const float gmy = ws[1*PNUM + j];
        const float gA  = ws[2*PNUM + j];
        const float gB  = ws[3*PNUM + j];
        const float gC  = ws[4*PNUM + j];
        const float gop = ws[5*PNUM + j];
        const float dx = fx - gmx;
        const float dy = fy - gmy;
        const float power = fmaf(gA, dx*dx, fmaf(gB, dx*dy, gC*dy*dy));
        if (power > 0.f) continue;
        const float alpha = fminf(0.99f, gop * __expf(power));
        if (alpha < (1.0f / 255.0f)) continue;
        const float w = alpha * T;
        r = fmaf(w, ws[6*PNUM + j], r);
        g = fmaf(w, ws[7*PNUM + j], g);
        b = fmaf(w, ws[8*PNUM + j], b);
        T *= (1.f - alpha);
    }

    pr[wv * SEGW + lane] = r;
    pg[wv * SEGW + lane] = g;
    pb[wv * SEGW + lane] = b;
    pt[wv * SEGW + lane] = T;
    __syncthreads();

    // ordered merge of the 8 chunk partials
    if (tid < SEGW) {
        float Tc = 1.f, ar = 0.f, ag = 0.f, ab = 0.f;
        #pragma unroll
        for (int c = 0; c < NCH; ++c) {
            ar = fmaf(Tc, pr[c * SEGW + tid], ar);
            ag = fmaf(Tc, pg[c * SEGW + tid], ag);
            ab = fmaf(Tc, pb[c * SEGW + tid], ab);
            Tc *= pt[c * SEGW + tid];
        }
        const int pix = row * IMW + x0 + tid;
        out[pix]          = ar;
        out[65536 + pix]  = ag;
        out[131072 + pix] = ab;
    }
}

extern "C" void kernel_launch(void* const* d_in, const int* in_sizes, int n_in,
                              void* d_out, int out_size, void* d_ws, size_t ws_size,
                              hipStream_t stream) {
    const float* points = (const float*)d_in[0];
    const float* scales = (const float*)d_in[1];
    const float* rots   = (const float*)d_in[2];
    const float* opac   = (const float*)d_in[3];
    const float* shs    = (const float*)d_in[4];
    const float* vm     = (const float*)d_in[5];
    float* out = (float*)d_out;
    float* ws  = (float*)d_ws;

    gr_preprocess<<<1, PNUM, 0, stream>>>(points, scales, rots, opac, shs, vm, out, ws);
    gr_rasterize<<<IMH * (IMW / SEGW), 512, 0, stream>>>(ws, out);
}

// Round 4
// 72.759 us; speedup vs baseline: 2.4763x; 1.1404x over previous
//
#include <hip/hip_runtime.h>
#include <math.h>

#define PNUM 512
#define IMW 256
#define IMH 256
#define NCH 8      // waves per block
#define SEGW 64    // pixels per block (one 64-wide row segment)

// Single fused kernel. Each block owns one 64-px row segment:
//   A) 512 threads redundantly preprocess all 512 gaussians (1 each, registers)
//   B) exact-safe cull vs this segment (alpha >= 1/255 lower bound)
//   C) ballot-compact survivor (tz, idx) keys; O(L^2) rank-sort (L ~ 15);
//      scatter survivor params from registers into depth-sorted LDS slots
//   D) 8-wave chunked front-to-back composite + ordered LDS merge
// No workspace, no inter-block communication, one launch.
__global__ __launch_bounds__(512, 4) void gr_fused(
    const float* __restrict__ points, const float* __restrict__ scales,
    const float* __restrict__ rots, const float* __restrict__ opac_in,
    const float* __restrict__ shs, const float* __restrict__ vm,
    float* __restrict__ out)
{
    __shared__ float k_tz[PNUM];
    __shared__ int   k_id[PNUM];
    __shared__ float smx[PNUM], smy[PNUM], sA[PNUM], sB[PNUM], sC[PNUM];
    __shared__ float sop[PNUM], scr[PNUM], scg[PNUM], scb[PNUM];
    __shared__ float pr[NCH*SEGW], pg[NCH*SEGW], pb[NCH*SEGW], pt[NCH*SEGW];
    __shared__ int scnt[NCH];

    const int tid  = threadIdx.x;      // gaussian id in phases A-C
    const int lane = tid & 63;
    const int wv   = tid >> 6;
    const int seg  = blockIdx.x;
    const int row  = seg >> 2;
    const int x0   = (seg & 3) << 6;
    const float fy = (float)row;

    // ---- A: per-gaussian preprocess (gaussian i = tid) ----
    const int i = tid;
    const float px = points[3*i], py = points[3*i+1], pz = points[3*i+2];
    const float sx = __expf(scales[3*i]), sy = __expf(scales[3*i+1]), sz = __expf(scales[3*i+2]);
    const float op0 = 1.0f / (1.0f + __expf(-opac_in[i]));
    const float q0 = rots[4*i], q1 = rots[4*i+1], q2 = rots[4*i+2], q3 = rots[4*i+3];
    const float qinv = 1.0f / sqrtf(q0*q0 + q1*q1 + q2*q2 + q3*q3);
    const float r = q0*qinv, x = q1*qinv, y = q2*qinv, z = q3*qinv;

    const float R00 = 1.f - 2.f*(y*y + z*z);
    const float R01 = 2.f*(x*y - r*z);
    const float R02 = 2.f*(x*z + r*y);
    const float R10 = 2.f*(x*y + r*z);
    const float R11 = 1.f - 2.f*(x*x + z*z);
    const float R12 = 2.f*(y*z - r*x);
    const float R20 = 2.f*(x*z - r*y);
    const float R21 = 2.f*(y*z + r*x);
    const float R22 = 1.f - 2.f*(x*x + y*y);

    const float M00=R00*sx, M01=R01*sy, M02=R02*sz;
    const float M10=R10*sx, M11=R11*sy, M12=R12*sz;
    const float M20=R20*sx, M21=R21*sy, M22=R22*sz;

    const float S00 = M00*M00 + M01*M01 + M02*M02;
    const float S01 = M00*M10 + M01*M11 + M02*M12;
    const float S02 = M00*M20 + M01*M21 + M02*M22;
    const float S11 = M10*M10 + M11*M11 + M12*M12;
    const float S12 = M10*M20 + M11*M21 + M12*M22;
    const float S22 = M20*M20 + M21*M21 + M22*M22;

    const float W00=vm[0], W01=vm[1], W02=vm[2],  T0=vm[3];
    const float W10=vm[4], W11=vm[5], W12=vm[6],  T1=vm[7];
    const float W20=vm[8], W21=vm[9], W22=vm[10], T2=vm[11];
    const float tx = W00*px + W01*py + W02*pz + T0;
    const float ty = W10*px + W11*py + W12*pz + T1;
    const float tz = W20*px + W21*py + W22*pz + T2;

    bool vis = tz > 0.2f;
    const float tzs = vis ? tz : 1.0f;
    const float lim = 1.3f * 0.5f;
    const float txtz = fminf(fmaxf(tx / tzs, -lim), lim) * tzs;
    const float tytz = fminf(fmaxf(ty / tzs, -lim), lim) * tzs;

    const float FX = 256.0f, FY = 256.0f;
    const float J00 = FX / tzs;
    const float J02 = -FX * txtz / (tzs * tzs);
    const float J11 = FY / tzs;
    const float J12 = -FY * tytz / (tzs * tzs);

    const float Tm00 = J00*W00 + J02*W20;
    const float Tm01 = J00*W01 + J02*W21;
    const float Tm02 = J00*W02 + J02*W22;
    const float Tm10 = J11*W10 + J12*W20;
    const float Tm11 = J11*W11 + J12*W21;
    const float Tm12 = J11*W12 + J12*W22;

    const float U00 = Tm00*S00 + Tm01*S01 + Tm02*S02;
    const float U01 = Tm00*S01 + Tm01*S11 + Tm02*S12;
    const float U02 = Tm00*S02 + Tm01*S12 + Tm02*S22;
    const float U10 = Tm10*S00 + Tm11*S01 + Tm12*S02;
    const float U11 = Tm10*S01 + Tm11*S11 + Tm12*S12;
    const float U12 = Tm10*S02 + Tm11*S12 + Tm12*S22;

    const float cov00 = U00*Tm00 + U01*Tm01 + U02*Tm02;
    const float cov01 = U00*Tm10 + U01*Tm11 + U02*Tm12;
    const float cov11 = U10*Tm10 + U11*Tm11 + U12*Tm12;

    const float det_orig = cov00*cov11 - cov01*cov01;
    const float a = cov00 + 0.3f, c = cov11 + 0.3f, b = cov01;
    const float det = a*c - b*b;
    vis = vis && (det > 0.f);
    const float dets = (det > 0.f) ? det : 1.0f;
    const float compn = sqrtf(fmaxf(det_orig / dets, 0.f));
    const float op = vis ? op0 * compn : 0.f;
    const float invdet = 1.0f / dets;
    const float A2 = -0.5f * c * invdet;   // -0.5*conA
    const float B2 = b * invdet;           // -conB = -(-b/det)
    const float C2 = -0.5f * a * invdet;   // -0.5*conC

    const float mid = 0.5f * (a + c);
    const float lam = mid + sqrtf(fmaxf(mid*mid - det, 0.1f));

    const float mx = FX * tx / tzs + (IMW - 1) * 0.5f;
    const float my = FY * ty / tzs + (IMH - 1) * 0.5f;

    const float SH_C0 = 0.28209479177387814f;
    const float cr = fmaxf(shs[3*i  ] * SH_C0 + 0.5f, 0.f);
    const float cg = fmaxf(shs[3*i+1] * SH_C0 + 0.5f, 0.f);
    const float cb = fmaxf(shs[3*i+2] * SH_C0 + 0.5f, 0.f);

    // alpha >= 1/255 requires |d|^2 <= 2*lam*ln(255*op) (lam >= lambda_max)
    float rc2 = -1.f;
    const float p255 = 255.f * op;
    if (p255 > 1.f) rc2 = 2.f * lam * __logf(p255) * 1.001f + 0.01f;

    // aux outputs (one block writes; all blocks computed them anyway)
    if (seg == 0) {
        const float radii = vis ? ceilf(3.f * sqrtf(lam)) : 0.f;
        out[196608 + 3*i + 0] = 0.f;
        out[196608 + 3*i + 1] = 0.f;
        out[196608 + 3*i + 2] = 0.f;
        out[198144 + i] = radii;
    }

    // ---- B: exact-safe cull vs this segment ----
    const float dxl = (float)x0 - mx;
    const float dxr = mx - (float)(x0 + SEGW - 1);
    const float dxm = fmaxf(0.f, fmaxf(dxl, dxr));
    const float dym = fabsf(fy - my);
    const bool hit = (dxm*dxm + dym*dym) <= rc2;   // rc2<0 => never

    // ---- C: compact survivor keys, rank-sort by (tz, idx), scatter ----
    const unsigned long long mball = __ballot(hit);
    if (lane == 0) scnt[wv] = __popcll(mball);
    __syncthreads();
    int base = 0, L = 0;
    #pragma unroll
    for (int w = 0; w < NCH; ++w) { L += scnt[w]; if (w < wv) base += scnt[w]; }
    if (hit) {
        const int pos = base + __popcll(mball & ((1ull << lane) - 1ull));
        k_tz[pos] = tz;
        k_id[pos] = tid;
    }
    __syncthreads();

    if (hit) {
        int rank = 0;
        for (int j = 0; j < L; ++j) {
            const float kj = k_tz[j];
            rank += (kj < tz || (kj == tz && k_id[j] < tid)) ? 1 : 0;
        }
        smx[rank] = mx;  smy[rank] = my;
        sA[rank]  = A2;  sB[rank]  = B2;  sC[rank] = C2;
        sop[rank] = op;  scr[rank] = cr;  scg[rank] = cg;  scb[rank] = cb;
    }
    __syncthreads();

    // ---- D: chunked front-to-back composite over sorted survivors ----
    const int Lc = (L + NCH - 1) / NCH;
    const int k0 = wv * Lc;
    const int k1 = (k0 + Lc < L) ? (k0 + Lc) : L;

    const float fx = (float)(x0 + lane);
    float T = 1.f, ar = 0.f, ag = 0.f, ab = 0.f;

    for (int k = k0; k < k1; ++k) {
        const float dx = fx - smx[k];
        const float dy = fy - smy[k];
        const float power = fmaf(sA[k], dx*dx, fmaf(sB[k], dx*dy, sC[k]*dy*dy));
        if (power > 0.f) continue;
        const float alpha = fminf(0.99f, sop[k] * __expf(power));
        if (alpha < (1.0f / 255.0f)) continue;
        const float w = alpha * T;
        ar = fmaf(w, scr[k], ar);
        ag = fmaf(w, scg[k], ag);
        ab = fmaf(w, scb[k], ab);
        T *= (1.f - alpha);
    }

    pr[wv * SEGW + lane] = ar;
    pg[wv * SEGW + lane] = ag;
    pb[wv * SEGW + lane] = ab;
    pt[wv * SEGW + lane] = T;
    __syncthreads();

    if (tid < SEGW) {
        float Tc = 1.f, rr = 0.f, gg = 0.f, bb = 0.f;
        #pragma unroll
        for (int c2 = 0; c2 < NCH; ++c2) {
            rr = fmaf(Tc, pr[c2 * SEGW + tid], rr);
            gg = fmaf(Tc, pg[c2 * SEGW + tid], gg);
            bb = fmaf(Tc, pb[c2 * SEGW + tid], bb);
            Tc *= pt[c2 * SEGW + tid];
        }
        const int pix = row * IMW + x0 + tid;
        out[pix]          = rr;
        out[65536 + pix]  = gg;
        out[131072 + pix] = bb;
    }
}

extern "C" void kernel_launch(void* const* d_in, const int* in_sizes, int n_in,
                              void* d_out, int out_size, void* d_ws, size_t ws_size,
                              hipStream_t stream) {
    const float* points = (const float*)d_in[0];
    const float* scales = (const float*)d_in[1];
    const float* rots   = (const float*)d_in[2];
    const float* opac   = (const float*)d_in[3];
    const float* shs    = (const float*)d_in[4];
    const float* vm     = (const float*)d_in[5];
    float* out = (float*)d_out;

    gr_fused<<<IMH * (IMW / SEGW), 512, 0, stream>>>(points, scales, rots, opac, shs, vm, out);
}